// Round 1
// baseline (5165.249 us; speedup 1.0000x reference)
//
#include <hip/hip_runtime.h>
#include <hip/hip_bf16.h>

// Problem constants (validated against in_sizes at launch)
// N = 50000 nodes, E = 800000 edges, F_IN = F_OUT = 128.

__device__ __forceinline__ void fma4(float4& a, const float4 w, const float s) {
    a.x = fmaf(w.x, s, a.x);
    a.y = fmaf(w.y, s, a.y);
    a.z = fmaf(w.z, s, a.z);
    a.w = fmaf(w.w, s, a.w);
}

// ---------------------------------------------------------------------------
// Kernel 1: transpose the 4 weight matrices [128][128] (row c, col k) into
// wT[m][k][c]. 65536 elements total — negligible cost.
// ---------------------------------------------------------------------------
__global__ __launch_bounds__(256) void wpose_kernel(
    const float* __restrict__ wpl, const float* __restrict__ wpr,
    const float* __restrict__ wnl, const float* __restrict__ wnr,
    float* __restrict__ wT) {
    int id = blockIdx.x * 256 + threadIdx.x;      // 0 .. 65535
    int m   = id >> 14;
    int rem = id & 16383;
    int k   = rem >> 7;
    int c   = rem & 127;
    const float* w = (m == 0) ? wpl : (m == 1) ? wpr : (m == 2) ? wnl : wnr;
    wT[id] = w[c * 128 + k];                      // wT[m][k][c] = w[c][k]
}

// ---------------------------------------------------------------------------
// Kernel 2: tiled transpose x[N][128] -> xT[128][N]
// ---------------------------------------------------------------------------
__global__ __launch_bounds__(256) void xpose_kernel(
    const float* __restrict__ x, float* __restrict__ xT, int N) {
    __shared__ float tile[32][33];
    int n0 = blockIdx.x * 32;
    int k0 = blockIdx.y * 32;
    int tx = threadIdx.x & 31;
    int ty = threadIdx.x >> 5;   // 0..7
#pragma unroll
    for (int i = 0; i < 4; ++i) {
        int n = n0 + ty + i * 8;
        tile[ty + i * 8][tx] = (n < N) ? x[(size_t)n * 128 + k0 + tx] : 0.f;
    }
    __syncthreads();
#pragma unroll
    for (int i = 0; i < 4; ++i) {
        int k = k0 + ty + i * 8;
        int n = n0 + tx;
        if (n < N) xT[(size_t)k * N + n] = tile[tx][ty + i * 8];
    }
}

// ---------------------------------------------------------------------------
// Kernel 3: edge scatter. 32 lanes per edge; each lane handles 4 features
// (float4 gather of x[src]), scaled by |w|, atomically added into the
// k-major accumulator aT[sign][k][dst]. Lane 0 bumps the edge count.
// ---------------------------------------------------------------------------
__global__ __launch_bounds__(256) void edge_kernel(
    const float* __restrict__ x, const int* __restrict__ ei,
    const float* __restrict__ attr, float* __restrict__ aT,
    float* __restrict__ cnt, int E, int N) {
    int t = blockIdx.x * 256 + threadIdx.x;
    int e = t >> 5;
    if (e >= E) return;
    int lane = t & 31;

    float w = attr[e];
    if (w == 0.f) return;                 // excluded from both masks
    int   h  = (w > 0.f) ? 0 : 1;
    float aw = fabsf(w);

    int src = ei[e];
    int dst = ei[E + e];

    const float4 xr = ((const float4*)(x + (size_t)src * 128))[lane];
    float* base = aT + (size_t)h * 128 * N;
    int c0 = lane * 4;
    atomicAdd(base + (size_t)(c0 + 0) * N + dst, xr.x * aw);
    atomicAdd(base + (size_t)(c0 + 1) * N + dst, xr.y * aw);
    atomicAdd(base + (size_t)(c0 + 2) * N + dst, xr.z * aw);
    atomicAdd(base + (size_t)(c0 + 3) * N + dst, xr.w * aw);
    if (lane == 0) atomicAdd(cnt + (size_t)h * N + dst, 1.f);
}

// ---------------------------------------------------------------------------
// Kernel 4: per-half output GEMM + mean-division + bias + ReLU.
// grid = (ceil(N/32), 2). Block 256 threads.
// LDS: both weight matrices of this half, transposed [k][c] (128 KB).
// Thread (cg, nq): outputs c = 4*cg..+3, nodes n0 = tile + 4*nq..+3.
// out[n][h*128 + c] = relu( (sum_k wl[c][k]*aggsum[n][k]) / max(cnt,1)
//                         +  sum_k wr[c][k]*x[n][k] + b[c] )
// ---------------------------------------------------------------------------
__global__ __launch_bounds__(256) void out_kernel(
    const float* __restrict__ xT, const float* __restrict__ aT,
    const float* __restrict__ cnt, const float* __restrict__ wT,
    const float* __restrict__ bpos, const float* __restrict__ bneg,
    float* __restrict__ out, int N) {
    __shared__ float wls[128 * 128];
    __shared__ float wrs[128 * 128];

    const int h = blockIdx.y;
    const float4* wl_g = (const float4*)(wT + (size_t)(h * 2 + 0) * 16384);
    const float4* wr_g = (const float4*)(wT + (size_t)(h * 2 + 1) * 16384);
    float4* wls4 = (float4*)wls;
    float4* wrs4 = (float4*)wrs;
    for (int i = threadIdx.x; i < 4096; i += 256) {
        wls4[i] = wl_g[i];
        wrs4[i] = wr_g[i];
    }
    __syncthreads();

    const int tile_n = blockIdx.x * 32;
    const int cg = threadIdx.x & 31;   // output quad
    const int nq = threadIdx.x >> 5;   // node quad
    const int n0 = tile_n + nq * 4;

    if (n0 + 4 > N) return;            // N % 4 == 0: all-or-nothing per thread

    const float* aTh = aT + (size_t)h * 128 * N;

    float4 accl[4], accr[4];
#pragma unroll
    for (int j = 0; j < 4; ++j) {
        accl[j] = make_float4(0.f, 0.f, 0.f, 0.f);
        accr[j] = make_float4(0.f, 0.f, 0.f, 0.f);
    }

#pragma unroll 4
    for (int k = 0; k < 128; ++k) {
        const float4 wl4 = *(const float4*)(wls + k * 128 + cg * 4);
        const float4 wr4 = *(const float4*)(wrs + k * 128 + cg * 4);
        const float4 av = *(const float4*)(aTh + (size_t)k * N + n0);
        const float4 xv = *(const float4*)(xT + (size_t)k * N + n0);
        fma4(accl[0], wl4, av.x);
        fma4(accl[1], wl4, av.y);
        fma4(accl[2], wl4, av.z);
        fma4(accl[3], wl4, av.w);
        fma4(accr[0], wr4, xv.x);
        fma4(accr[1], wr4, xv.y);
        fma4(accr[2], wr4, xv.z);
        fma4(accr[3], wr4, xv.w);
    }

    const float4 b4 = *(const float4*)(((h == 0) ? bpos : bneg) + cg * 4);
#pragma unroll
    for (int j = 0; j < 4; ++j) {
        int n = n0 + j;
        float cv  = cnt[(size_t)h * N + n];
        float inv = 1.f / fmaxf(cv, 1.f);
        float4 o;
        o.x = fmaxf(fmaf(accl[j].x, inv, accr[j].x) + b4.x, 0.f);
        o.y = fmaxf(fmaf(accl[j].y, inv, accr[j].y) + b4.y, 0.f);
        o.z = fmaxf(fmaf(accl[j].z, inv, accr[j].z) + b4.z, 0.f);
        o.w = fmaxf(fmaf(accl[j].w, inv, accr[j].w) + b4.w, 0.f);
        *(float4*)(out + (size_t)n * 256 + h * 128 + cg * 4) = o;
    }
}

// ---------------------------------------------------------------------------
extern "C" void kernel_launch(void* const* d_in, const int* in_sizes, int n_in,
                              void* d_out, int out_size, void* d_ws, size_t ws_size,
                              hipStream_t stream) {
    const float* x    = (const float*)d_in[0];
    const int*   ei   = (const int*)d_in[1];
    const float* attr = (const float*)d_in[2];
    const float* wpl  = (const float*)d_in[3];
    const float* wpr  = (const float*)d_in[4];
    const float* bpos = (const float*)d_in[5];
    const float* wnl  = (const float*)d_in[6];
    const float* wnr  = (const float*)d_in[7];
    const float* bneg = (const float*)d_in[8];
    float* out = (float*)d_out;

    const int N = in_sizes[0] / 128;   // 50000
    const int E = in_sizes[2];         // 800000

    // Workspace layout (floats):
    //   aT  [2][128][N]   sign-split k-major aggregation sums
    //   cnt [2][N]        per-sign edge counts
    //   xT  [128][N]      transposed features
    //   wT  [4][128][128] transposed weights (pos_l, pos_r, neg_l, neg_r)
    float* ws  = (float*)d_ws;
    float* aT  = ws;
    float* cntp = aT + (size_t)2 * 128 * N;
    float* xT  = cntp + (size_t)2 * N;
    float* wT  = xT + (size_t)128 * N;

    // Zero the accumulators (aT + cnt are contiguous).
    hipMemsetAsync(aT, 0, (size_t)(2 * 128 * N + 2 * N) * sizeof(float), stream);

    wpose_kernel<<<256, 256, 0, stream>>>(wpl, wpr, wnl, wnr, wT);
    xpose_kernel<<<dim3((N + 31) / 32, 4), 256, 0, stream>>>(x, xT, N);
    edge_kernel<<<(E * 32 + 255) / 256, 256, 0, stream>>>(x, ei, attr, aT, cntp, E, N);
    out_kernel<<<dim3((N + 31) / 32, 2), 256, 0, stream>>>(xT, aT, cntp, wT, bpos, bneg, out, N);
}

// Round 2
// 376.378 us; speedup vs baseline: 13.7236x; 13.7236x over previous
//
#include <hip/hip_runtime.h>
#include <hip/hip_bf16.h>

// N = 50000 nodes, E = 800000 edges, F_IN = F_OUT = 128.
// Strategy: CSR-by-(sign,dst) build (int atomics only), then atomic-free
// per-row weighted aggregation, then fused GEMM+mean+bias+ReLU.

#define SCAN_CHUNK 1024

__device__ __forceinline__ void fma4(float4& a, const float4 w, const float s) {
    a.x = fmaf(w.x, s, a.x);
    a.y = fmaf(w.y, s, a.y);
    a.z = fmaf(w.z, s, a.z);
    a.w = fmaf(w.w, s, a.w);
}

// ---------------------------------------------------------------------------
// Transpose the 4 weight matrices [128][128] (row c, col k) into wT[m][k][c].
// ---------------------------------------------------------------------------
__global__ __launch_bounds__(256) void wpose_kernel(
    const float* __restrict__ wpl, const float* __restrict__ wpr,
    const float* __restrict__ wnl, const float* __restrict__ wnr,
    float* __restrict__ wT) {
    int id = blockIdx.x * 256 + threadIdx.x;      // 0 .. 65535
    int m   = id >> 14;
    int rem = id & 16383;
    int k   = rem >> 7;
    int c   = rem & 127;
    const float* w = (m == 0) ? wpl : (m == 1) ? wpr : (m == 2) ? wnl : wnr;
    wT[id] = w[c * 128 + k];                      // wT[m][k][c] = w[c][k]
}

// ---------------------------------------------------------------------------
// Tiled transpose x[N][128] -> xT[128][N]
// ---------------------------------------------------------------------------
__global__ __launch_bounds__(256) void xpose_kernel(
    const float* __restrict__ x, float* __restrict__ xT, int N) {
    __shared__ float tile[32][33];
    int n0 = blockIdx.x * 32;
    int k0 = blockIdx.y * 32;
    int tx = threadIdx.x & 31;
    int ty = threadIdx.x >> 5;   // 0..7
#pragma unroll
    for (int i = 0; i < 4; ++i) {
        int n = n0 + ty + i * 8;
        tile[ty + i * 8][tx] = (n < N) ? x[(size_t)n * 128 + k0 + tx] : 0.f;
    }
    __syncthreads();
#pragma unroll
    for (int i = 0; i < 4; ++i) {
        int k = k0 + ty + i * 8;
        int n = n0 + tx;
        if (n < N) xT[(size_t)k * N + n] = tile[tx][ty + i * 8];
    }
}

// ---------------------------------------------------------------------------
// CSR build pass 1: per-(sign,dst) edge counts (int atomics, L2-resident).
// ---------------------------------------------------------------------------
__global__ __launch_bounds__(256) void count_kernel(
    const int* __restrict__ ei, const float* __restrict__ attr,
    int* __restrict__ counts, int E, int N) {
    int e = blockIdx.x * 256 + threadIdx.x;
    if (e >= E) return;
    float w = attr[e];
    if (w == 0.f) return;
    int h = (w > 0.f) ? 0 : 1;
    int dst = ei[E + e];
    atomicAdd(&counts[h * N + dst], 1);
}

// ---------------------------------------------------------------------------
// Exclusive scan over counts[0..n) in 3 kernels (chunk = 1024).
// ---------------------------------------------------------------------------
__global__ __launch_bounds__(256) void scan_k1(
    const int* __restrict__ counts, int* __restrict__ partial, int n) {
    __shared__ int sd[256];
    int b = blockIdx.x, t = threadIdx.x;
    int idx = b * SCAN_CHUNK + t * 4;
    int s = 0;
#pragma unroll
    for (int j = 0; j < 4; ++j) { int i = idx + j; if (i < n) s += counts[i]; }
    sd[t] = s;
    __syncthreads();
    for (int off = 128; off > 0; off >>= 1) {
        if (t < off) sd[t] += sd[t + off];
        __syncthreads();
    }
    if (t == 0) partial[b] = sd[0];
}

__global__ void scan_k2(const int* __restrict__ partial, int* __restrict__ base, int nb) {
    if (threadIdx.x == 0 && blockIdx.x == 0) {
        int run = 0;
        for (int i = 0; i < nb; ++i) { base[i] = run; run += partial[i]; }
    }
}

__global__ __launch_bounds__(256) void scan_k3(
    const int* __restrict__ counts, const int* __restrict__ base,
    int* __restrict__ offs, int* __restrict__ cursor, int n) {
    __shared__ int sd[256];
    int b = blockIdx.x, t = threadIdx.x;
    int idx = b * SCAN_CHUNK + t * 4;
    int c[4]; int s = 0;
#pragma unroll
    for (int j = 0; j < 4; ++j) { int i = idx + j; c[j] = (i < n) ? counts[i] : 0; s += c[j]; }
    sd[t] = s;
    __syncthreads();
    for (int off = 1; off < 256; off <<= 1) {   // inclusive Hillis-Steele
        int v = (t >= off) ? sd[t - off] : 0;
        __syncthreads();
        sd[t] += v;
        __syncthreads();
    }
    int run = base[b] + sd[t] - s;              // exclusive prefix for this thread
#pragma unroll
    for (int j = 0; j < 4; ++j) {
        int i = idx + j;
        if (i < n) { offs[i] = run; cursor[i] = run; run += c[j]; }
    }
}

// ---------------------------------------------------------------------------
// CSR build pass 2: scatter packed (src, |w|) into per-row segments.
// ---------------------------------------------------------------------------
__global__ __launch_bounds__(256) void scatter_kernel(
    const int* __restrict__ ei, const float* __restrict__ attr,
    int* __restrict__ cursor, int* __restrict__ srcs, float* __restrict__ wabs,
    int E, int N) {
    int e = blockIdx.x * 256 + threadIdx.x;
    if (e >= E) return;
    float w = attr[e];
    if (w == 0.f) return;
    int h = (w > 0.f) ? 0 : 1;
    int dst = ei[E + e];
    int slot = atomicAdd(&cursor[h * N + dst], 1);
    srcs[slot] = ei[e];
    wabs[slot] = fabsf(w);
}

// ---------------------------------------------------------------------------
// Aggregation: one wave per CSR row (= one (sign,dst) pair). 64 lanes hold
// the 128-float row (float2 each); per edge: broadcast (src,|w|) read,
// coalesced 512B gather of x[src], fma. Next-edge operands are prefetched to
// break the load->gather dependence. Block = 4 waves = 64 consecutive rows;
// result transposed through LDS and stored k-major (stride 2N), coalesced.
// ---------------------------------------------------------------------------
__global__ __launch_bounds__(256) void agg_kernel(
    const float* __restrict__ x, const int* __restrict__ srcs,
    const float* __restrict__ wabs, const int* __restrict__ counts,
    const int* __restrict__ offs, float* __restrict__ aggT, int twoN) {
    __shared__ float ts[128][65];
    const int r0   = blockIdx.x * 64;
    const int lane = threadIdx.x & 63;
    const int wv   = threadIdx.x >> 6;

    for (int i = 0; i < 16; ++i) {
        const int dloc = wv * 16 + i;
        const int r = r0 + dloc;
        if (r < twoN) {
            const int cn  = counts[r];
            const int beg = offs[r];
            float a0 = 0.f, a1 = 0.f;
            int s = 0; float w = 0.f;
            if (cn > 0) { s = srcs[beg]; w = wabs[beg]; }
            for (int j = 0; j < cn; ++j) {
                const int sc = s; const float wc = w;
                if (j + 1 < cn) { s = srcs[beg + j + 1]; w = wabs[beg + j + 1]; }
                const float2 xv = ((const float2*)(x + (size_t)sc * 128))[lane];
                a0 = fmaf(xv.x, wc, a0);
                a1 = fmaf(xv.y, wc, a1);
            }
            ts[2 * lane + 0][dloc] = a0;
            ts[2 * lane + 1][dloc] = a1;
        }
    }
    __syncthreads();

    const int d  = threadIdx.x & 63;
    const int kb = threadIdx.x >> 6;   // 0..3
    if (r0 + d < twoN) {
        float* dst = aggT + r0 + d;
#pragma unroll
        for (int k4 = 0; k4 < 32; ++k4) {
            const int k = kb + k4 * 4;
            dst[(size_t)k * twoN] = ts[k][d];
        }
    }
}

// ---------------------------------------------------------------------------
// Output GEMM + mean + bias + ReLU. grid = (ceil(N/64), 2), block 512.
// LDS: this half's two transposed weight matrices (128 KB).
// Thread (cg, nq): outputs c = 4*cg..+3 for nodes n0..n0+3.
// ---------------------------------------------------------------------------
__global__ __launch_bounds__(512) void out_kernel(
    const float* __restrict__ xT, const float* __restrict__ aggT,
    const int* __restrict__ counts, const float* __restrict__ wT,
    const float* __restrict__ bpos, const float* __restrict__ bneg,
    float* __restrict__ out, int N) {
    __shared__ float wls[128 * 128];
    __shared__ float wrs[128 * 128];

    const int h = blockIdx.y;
    const int twoN = 2 * N;
    const float4* wl_g = (const float4*)(wT + (size_t)(h * 2 + 0) * 16384);
    const float4* wr_g = (const float4*)(wT + (size_t)(h * 2 + 1) * 16384);
    float4* wls4 = (float4*)wls;
    float4* wrs4 = (float4*)wrs;
    for (int i = threadIdx.x; i < 4096; i += 512) {
        wls4[i] = wl_g[i];
        wrs4[i] = wr_g[i];
    }
    __syncthreads();

    const int tile_n = blockIdx.x * 64;
    const int cg = threadIdx.x & 31;   // output quad
    const int nq = threadIdx.x >> 5;   // node quad (0..15)
    const int n0 = tile_n + nq * 4;
    if (n0 + 4 > N) return;            // N % 4 == 0

    const float* aTh = aggT + (size_t)h * N;

    float4 accl[4], accr[4];
#pragma unroll
    for (int j = 0; j < 4; ++j) {
        accl[j] = make_float4(0.f, 0.f, 0.f, 0.f);
        accr[j] = make_float4(0.f, 0.f, 0.f, 0.f);
    }

#pragma unroll 4
    for (int k = 0; k < 128; ++k) {
        const float4 wl4 = *(const float4*)(wls + k * 128 + cg * 4);
        const float4 wr4 = *(const float4*)(wrs + k * 128 + cg * 4);
        const float4 av = *(const float4*)(aTh + (size_t)k * twoN + n0);
        const float4 xv = *(const float4*)(xT + (size_t)k * N + n0);
        fma4(accl[0], wl4, av.x);
        fma4(accl[1], wl4, av.y);
        fma4(accl[2], wl4, av.z);
        fma4(accl[3], wl4, av.w);
        fma4(accr[0], wr4, xv.x);
        fma4(accr[1], wr4, xv.y);
        fma4(accr[2], wr4, xv.z);
        fma4(accr[3], wr4, xv.w);
    }

    const float4 b4 = *(const float4*)(((h == 0) ? bpos : bneg) + cg * 4);
#pragma unroll
    for (int j = 0; j < 4; ++j) {
        int n = n0 + j;
        float cv  = (float)counts[h * N + n];
        float inv = 1.f / fmaxf(cv, 1.f);
        float4 o;
        o.x = fmaxf(fmaf(accl[j].x, inv, accr[j].x) + b4.x, 0.f);
        o.y = fmaxf(fmaf(accl[j].y, inv, accr[j].y) + b4.y, 0.f);
        o.z = fmaxf(fmaf(accl[j].z, inv, accr[j].z) + b4.z, 0.f);
        o.w = fmaxf(fmaf(accl[j].w, inv, accr[j].w) + b4.w, 0.f);
        *(float4*)(out + (size_t)n * 256 + h * 128 + cg * 4) = o;
    }
}

// ---------------------------------------------------------------------------
extern "C" void kernel_launch(void* const* d_in, const int* in_sizes, int n_in,
                              void* d_out, int out_size, void* d_ws, size_t ws_size,
                              hipStream_t stream) {
    const float* x    = (const float*)d_in[0];
    const int*   ei   = (const int*)d_in[1];
    const float* attr = (const float*)d_in[2];
    const float* wpl  = (const float*)d_in[3];
    const float* wpr  = (const float*)d_in[4];
    const float* bpos = (const float*)d_in[5];
    const float* wnl  = (const float*)d_in[6];
    const float* wnr  = (const float*)d_in[7];
    const float* bneg = (const float*)d_in[8];
    float* out = (float*)d_out;

    const int N = in_sizes[0] / 128;   // 50000
    const int E = in_sizes[2];         // 800000
    const int twoN = 2 * N;

    // Workspace layout:
    //   aggT   float [128][2N]   k-major aggregation sums (both signs)
    //   xT     float [128][N]
    //   wT     float [4][128][128]
    //   wabs   float [E]
    //   counts int   [2N]
    //   offs   int   [2N]
    //   cursor int   [2N]
    //   srcs   int   [E]
    //   partial,base int [256] each
    float* ws   = (float*)d_ws;
    float* aggT = ws;
    float* xT   = aggT + (size_t)128 * twoN;
    float* wT   = xT + (size_t)128 * N;
    float* wabs = wT + 4 * 128 * 128;
    int* counts = (int*)(wabs + E);
    int* offs   = counts + twoN;
    int* cursor = offs + twoN;
    int* srcs   = cursor + twoN;
    int* partial = srcs + E;
    int* scanbase = partial + 256;

    const int nchunk = (twoN + SCAN_CHUNK - 1) / SCAN_CHUNK;   // 98

    hipMemsetAsync(counts, 0, (size_t)twoN * sizeof(int), stream);

    wpose_kernel<<<256, 256, 0, stream>>>(wpl, wpr, wnl, wnr, wT);
    xpose_kernel<<<dim3((N + 31) / 32, 4), 256, 0, stream>>>(x, xT, N);
    count_kernel<<<(E + 255) / 256, 256, 0, stream>>>(ei, attr, counts, E, N);
    scan_k1<<<nchunk, 256, 0, stream>>>(counts, partial, twoN);
    scan_k2<<<1, 64, 0, stream>>>(partial, scanbase, nchunk);
    scan_k3<<<nchunk, 256, 0, stream>>>(counts, scanbase, offs, cursor, twoN);
    scatter_kernel<<<(E + 255) / 256, 256, 0, stream>>>(ei, attr, cursor, srcs, wabs, E, N);
    agg_kernel<<<(twoN + 63) / 64, 256, 0, stream>>>(x, srcs, wabs, counts, offs, aggT, twoN);
    out_kernel<<<dim3((N + 63) / 64, 2), 512, 0, stream>>>(xT, aggT, counts, wT, bpos, bneg, out, N);
}

// Round 3
// 204.462 us; speedup vs baseline: 25.2627x; 1.8408x over previous
//
#include <hip/hip_runtime.h>
#include <hip/hip_bf16.h>

// N = 50000, E = 800000, F_IN = F_OUT = 128.
// Pipeline: CSR build (int atomics) -> bf16 weighted-mean aggregation
// (atomic-free, row-major bf16 output, mean folded in) -> MFMA bf16 GEMM
// with fragment-packed weights (no LDS) + bias + ReLU.

#define SCAN_CHUNK 1024

typedef __attribute__((ext_vector_type(8))) short bf16x8;
typedef __attribute__((ext_vector_type(8))) unsigned short ushort8;
typedef __attribute__((ext_vector_type(4))) float f32x4;

__device__ __forceinline__ unsigned short f2bf(float f) {
    unsigned int u = __float_as_uint(f);
    unsigned int r = (u + 0x7fffu + ((u >> 16) & 1u)) >> 16;
    return (unsigned short)r;
}

// ---------------------------------------------------------------------------
// x[N][128] fp32 -> xh[N][128] bf16
// ---------------------------------------------------------------------------
__global__ __launch_bounds__(256) void xcvt_kernel(
    const float* __restrict__ x, unsigned short* __restrict__ xh, int total8) {
    int i = blockIdx.x * 256 + threadIdx.x;
    if (i >= total8) return;
    const float4* xp = (const float4*)x;
    float4 v0 = xp[2 * i];
    float4 v1 = xp[2 * i + 1];
    ushort8 o;
    o[0] = f2bf(v0.x); o[1] = f2bf(v0.y); o[2] = f2bf(v0.z); o[3] = f2bf(v0.w);
    o[4] = f2bf(v1.x); o[5] = f2bf(v1.y); o[6] = f2bf(v1.z); o[7] = f2bf(v1.w);
    *(ushort8*)(xh + (size_t)i * 8) = o;
}

// ---------------------------------------------------------------------------
// Pack weights into MFMA B-fragment order.
// B_h[k][c] (K=256: rows 0-127 = w_l_h^T, 128-255 = w_r_h^T), fragment
// layout for mfma_f32_16x16x32_bf16: lane l holds B[k=32*kk+8*(l>>4)+j][c=16*nr+(l&15)].
// Bfrag index = ((h*64 + kk*8 + nr)*64 + l)*8 + j.
// ---------------------------------------------------------------------------
__global__ __launch_bounds__(256) void bfrag_kernel(
    const float* __restrict__ wpl, const float* __restrict__ wpr,
    const float* __restrict__ wnl, const float* __restrict__ wnr,
    unsigned short* __restrict__ Bfrag) {
    int tid = blockIdx.x * 256 + threadIdx.x;   // 0..8191
    int l  = tid & 63;
    int nr = (tid >> 6) & 7;
    int kk = (tid >> 9) & 7;
    int h  = tid >> 12;
    const float* wl = h ? wnl : wpl;
    const float* wr = h ? wnr : wpr;
    int c  = nr * 16 + (l & 15);
    int k0 = kk * 32 + (l >> 4) * 8;
    ushort8 o;
#pragma unroll
    for (int j = 0; j < 8; ++j) {
        int k = k0 + j;
        float v = (k < 128) ? wl[c * 128 + k] : wr[c * 128 + (k - 128)];
        o[j] = f2bf(v);
    }
    *(ushort8*)(Bfrag + (size_t)tid * 8) = o;
}

// ---------------------------------------------------------------------------
// CSR build pass 1: per-(sign,dst) edge counts.
// ---------------------------------------------------------------------------
__global__ __launch_bounds__(256) void count_kernel(
    const int* __restrict__ ei, const float* __restrict__ attr,
    int* __restrict__ counts, int E, int N) {
    int e = blockIdx.x * 256 + threadIdx.x;
    if (e >= E) return;
    float w = attr[e];
    if (w == 0.f) return;
    int h = (w > 0.f) ? 0 : 1;
    int dst = ei[E + e];
    atomicAdd(&counts[h * N + dst], 1);
}

// ---------------------------------------------------------------------------
// Exclusive scan over counts[0..n): chunked (1024/block).
// ---------------------------------------------------------------------------
__global__ __launch_bounds__(256) void scan_k1(
    const int* __restrict__ counts, int* __restrict__ partial, int n) {
    __shared__ int sd[256];
    int b = blockIdx.x, t = threadIdx.x;
    int idx = b * SCAN_CHUNK + t * 4;
    int s = 0;
#pragma unroll
    for (int j = 0; j < 4; ++j) { int i = idx + j; if (i < n) s += counts[i]; }
    sd[t] = s;
    __syncthreads();
    for (int off = 128; off > 0; off >>= 1) {
        if (t < off) sd[t] += sd[t + off];
        __syncthreads();
    }
    if (t == 0) partial[b] = sd[0];
}

__global__ __launch_bounds__(128) void scan_k2(
    const int* __restrict__ partial, int* __restrict__ base, int nb) {
    __shared__ int sd[128];
    int t = threadIdx.x;
    int own = (t < nb) ? partial[t] : 0;
    sd[t] = own;
    __syncthreads();
    for (int off = 1; off < 128; off <<= 1) {
        int v = (t >= off) ? sd[t - off] : 0;
        __syncthreads();
        sd[t] += v;
        __syncthreads();
    }
    if (t < nb) base[t] = sd[t] - own;   // exclusive
}

__global__ __launch_bounds__(256) void scan_k3(
    const int* __restrict__ counts, const int* __restrict__ base,
    int* __restrict__ offs, int* __restrict__ cursor, int n) {
    __shared__ int sd[256];
    int b = blockIdx.x, t = threadIdx.x;
    int idx = b * SCAN_CHUNK + t * 4;
    int c[4]; int s = 0;
#pragma unroll
    for (int j = 0; j < 4; ++j) { int i = idx + j; c[j] = (i < n) ? counts[i] : 0; s += c[j]; }
    sd[t] = s;
    __syncthreads();
    for (int off = 1; off < 256; off <<= 1) {   // inclusive Hillis-Steele
        int v = (t >= off) ? sd[t - off] : 0;
        __syncthreads();
        sd[t] += v;
        __syncthreads();
    }
    int run = base[b] + sd[t] - s;
#pragma unroll
    for (int j = 0; j < 4; ++j) {
        int i = idx + j;
        if (i < n) { offs[i] = run; cursor[i] = run; run += c[j]; }
    }
}

// ---------------------------------------------------------------------------
// CSR build pass 2: scatter packed (src, |w|) into per-row segments.
// ---------------------------------------------------------------------------
__global__ __launch_bounds__(256) void scatter_kernel(
    const int* __restrict__ ei, const float* __restrict__ attr,
    int* __restrict__ cursor, int* __restrict__ srcs, float* __restrict__ wabs,
    int E, int N) {
    int e = blockIdx.x * 256 + threadIdx.x;
    if (e >= E) return;
    float w = attr[e];
    if (w == 0.f) return;
    int h = (w > 0.f) ? 0 : 1;
    int dst = ei[E + e];
    int slot = atomicAdd(&cursor[h * N + dst], 1);
    srcs[slot] = ei[e];
    wabs[slot] = fabsf(w);
}

// ---------------------------------------------------------------------------
// Aggregation: one wave per (sign,dst) row. Lane holds features 2l,2l+1.
// Per edge: 4B bf16x2 gather of xh[src], fp32 fma; next-edge (src,w)
// prefetched. Epilogue divides by count and stores bf16 row (coalesced).
// ---------------------------------------------------------------------------
__global__ __launch_bounds__(256) void agg_kernel(
    const unsigned short* __restrict__ xh, const int* __restrict__ srcs,
    const float* __restrict__ wabs, const int* __restrict__ counts,
    const int* __restrict__ offs, unsigned short* __restrict__ mh, int twoN) {
    const int r = blockIdx.x * 4 + (threadIdx.x >> 6);
    if (r >= twoN) return;
    const int lane = threadIdx.x & 63;
    const int cn  = counts[r];
    const int beg = offs[r];
    float a0 = 0.f, a1 = 0.f;
    int s = 0; float w = 0.f;
    if (cn > 0) { s = srcs[beg]; w = wabs[beg]; }
    for (int j = 0; j < cn; ++j) {
        const int sc = s; const float wc = w;
        if (j + 1 < cn) { s = srcs[beg + j + 1]; w = wabs[beg + j + 1]; }
        const unsigned v = *(const unsigned*)(xh + (size_t)sc * 128 + 2 * lane);
        a0 = fmaf(__uint_as_float(v << 16), wc, a0);
        a1 = fmaf(__uint_as_float(v & 0xffff0000u), wc, a1);
    }
    const float inv = 1.f / fmaxf((float)cn, 1.f);
    unsigned p = ((unsigned)f2bf(a1 * inv) << 16) | (unsigned)f2bf(a0 * inv);
    *(unsigned*)(mh + (size_t)r * 128 + 2 * lane) = p;
}

// ---------------------------------------------------------------------------
// Output GEMM via MFMA. grid = (ceil(N/128), 2), block 256 (4 waves).
// Wave w computes rows m0 = bx*128 + w*32 (2 M-frags), all 128 cols of its
// half. K=256: kk 0..3 read mean_h, kk 4..7 read x. A-frags loaded straight
// from global (16B/lane, row-major bf16); B-frags from fragment-packed
// global (coalesced 1KB/wave, L2-resident). No LDS, no barriers.
// out[n][h*128+c] = relu(acc + b_h[c]).
// ---------------------------------------------------------------------------
__global__ __launch_bounds__(256) void out_mfma(
    const unsigned short* __restrict__ mh, const unsigned short* __restrict__ xh,
    const unsigned short* __restrict__ Bfrag,
    const float* __restrict__ bpos, const float* __restrict__ bneg,
    float* __restrict__ out, int N) {
    const int h  = blockIdx.y;
    const int l  = threadIdx.x & 63;
    const int wv = threadIdx.x >> 6;
    const int m0 = blockIdx.x * 128 + wv * 32;
    const int lm = l & 15;
    const int lk = l >> 4;

    const unsigned short* Am = mh + (size_t)h * N * 128;
    const bf16x8* Bf = (const bf16x8*)Bfrag + (size_t)h * 4096;

    f32x4 acc[2][8];
#pragma unroll
    for (int mr = 0; mr < 2; ++mr)
#pragma unroll
        for (int nr = 0; nr < 8; ++nr)
            acc[mr][nr] = (f32x4){0.f, 0.f, 0.f, 0.f};

    int r0 = m0 + lm;       if (r0 > N - 1) r0 = N - 1;
    int r1 = m0 + 16 + lm;  if (r1 > N - 1) r1 = N - 1;

#pragma unroll
    for (int kk = 0; kk < 8; ++kk) {
        const unsigned short* Asrc = (kk < 4) ? Am : xh;
        const int kloc = (kk & 3) * 32 + lk * 8;
        bf16x8 a0 = *(const bf16x8*)(Asrc + (size_t)r0 * 128 + kloc);
        bf16x8 a1 = *(const bf16x8*)(Asrc + (size_t)r1 * 128 + kloc);
        const bf16x8* bk = Bf + kk * 8 * 64;
#pragma unroll
        for (int nr = 0; nr < 8; ++nr) {
            bf16x8 b = bk[nr * 64 + l];
            acc[0][nr] = __builtin_amdgcn_mfma_f32_16x16x32_bf16(a0, b, acc[0][nr], 0, 0, 0);
            acc[1][nr] = __builtin_amdgcn_mfma_f32_16x16x32_bf16(a1, b, acc[1][nr], 0, 0, 0);
        }
    }

    const float* bb = (h == 0) ? bpos : bneg;
#pragma unroll
    for (int nr = 0; nr < 8; ++nr) {
        const float bc = bb[nr * 16 + lm];
#pragma unroll
        for (int mr = 0; mr < 2; ++mr) {
#pragma unroll
            for (int rr = 0; rr < 4; ++rr) {
                const int row = m0 + mr * 16 + lk * 4 + rr;
                if (row < N)
                    out[(size_t)row * 256 + h * 128 + nr * 16 + lm] =
                        fmaxf(acc[mr][nr][rr] + bc, 0.f);
            }
        }
    }
}

// ---------------------------------------------------------------------------
extern "C" void kernel_launch(void* const* d_in, const int* in_sizes, int n_in,
                              void* d_out, int out_size, void* d_ws, size_t ws_size,
                              hipStream_t stream) {
    const float* x    = (const float*)d_in[0];
    const int*   ei   = (const int*)d_in[1];
    const float* attr = (const float*)d_in[2];
    const float* wpl  = (const float*)d_in[3];
    const float* wpr  = (const float*)d_in[4];
    const float* bpos = (const float*)d_in[5];
    const float* wnl  = (const float*)d_in[6];
    const float* wnr  = (const float*)d_in[7];
    const float* bneg = (const float*)d_in[8];
    float* out = (float*)d_out;

    const int N = in_sizes[0] / 128;   // 50000
    const int E = in_sizes[2];         // 800000
    const int twoN = 2 * N;

    // Workspace layout:
    //   mh     ushort [2N][128]   bf16 per-sign means (already divided)
    //   xh     ushort [N][128]    bf16 features
    //   Bfrag  ushort [2][4096][8] fragment-packed weights
    //   wabs   float  [E]
    //   counts,offs,cursor int [2N]
    //   srcs   int [E]
    //   partial,base int [128]
    unsigned short* mh    = (unsigned short*)d_ws;
    unsigned short* xh    = mh + (size_t)twoN * 128;
    unsigned short* Bfrag = xh + (size_t)N * 128;
    float* wabs  = (float*)(Bfrag + 65536);
    int* counts  = (int*)(wabs + E);
    int* offs    = counts + twoN;
    int* cursor  = offs + twoN;
    int* srcs    = cursor + twoN;
    int* partial = srcs + E;
    int* sbase   = partial + 128;

    const int nchunk = (twoN + SCAN_CHUNK - 1) / SCAN_CHUNK;   // 98 (<=128)

    hipMemsetAsync(counts, 0, (size_t)twoN * sizeof(int), stream);

    xcvt_kernel<<<(N * 16 + 255) / 256, 256, 0, stream>>>(x, xh, N * 16);
    bfrag_kernel<<<32, 256, 0, stream>>>(wpl, wpr, wnl, wnr, Bfrag);
    count_kernel<<<(E + 255) / 256, 256, 0, stream>>>(ei, attr, counts, E, N);
    scan_k1<<<nchunk, 256, 0, stream>>>(counts, partial, twoN);
    scan_k2<<<1, 128, 0, stream>>>(partial, sbase, nchunk);
    scan_k3<<<nchunk, 256, 0, stream>>>(counts, sbase, offs, cursor, twoN);
    scatter_kernel<<<(E + 255) / 256, 256, 0, stream>>>(ei, attr, cursor, srcs, wabs, E, N);
    agg_kernel<<<(twoN + 3) / 4, 256, 0, stream>>>(xh, srcs, wabs, counts, offs, mh, twoN);
    out_mfma<<<dim3((N + 127) / 128, 2), 256, 0, stream>>>(mh, xh, Bfrag, bpos, bneg, out, N);
}

// Round 4
// 202.217 us; speedup vs baseline: 25.5430x; 1.0111x over previous
//
#include <hip/hip_runtime.h>
#include <hip/hip_bf16.h>

// N = 50000, E = 800000, F_IN = F_OUT = 128.
// Pipeline: CSR build (int atomics) -> bf16 weighted-mean aggregation with
// 8-deep batched gathers (atomic-free, mean folded in) -> MFMA bf16 GEMM
// with fragment-packed weights (no LDS) + bias + ReLU.

#define SCAN_CHUNK 1024

typedef __attribute__((ext_vector_type(8))) short bf16x8;
typedef __attribute__((ext_vector_type(8))) unsigned short ushort8;
typedef __attribute__((ext_vector_type(4))) float f32x4;

__device__ __forceinline__ unsigned short f2bf(float f) {
    unsigned int u = __float_as_uint(f);
    unsigned int r = (u + 0x7fffu + ((u >> 16) & 1u)) >> 16;
    return (unsigned short)r;
}

// ---------------------------------------------------------------------------
// x[N][128] fp32 -> xh[N][128] bf16
// ---------------------------------------------------------------------------
__global__ __launch_bounds__(256) void xcvt_kernel(
    const float* __restrict__ x, unsigned short* __restrict__ xh, int total8) {
    int i = blockIdx.x * 256 + threadIdx.x;
    if (i >= total8) return;
    const float4* xp = (const float4*)x;
    float4 v0 = xp[2 * i];
    float4 v1 = xp[2 * i + 1];
    ushort8 o;
    o[0] = f2bf(v0.x); o[1] = f2bf(v0.y); o[2] = f2bf(v0.z); o[3] = f2bf(v0.w);
    o[4] = f2bf(v1.x); o[5] = f2bf(v1.y); o[6] = f2bf(v1.z); o[7] = f2bf(v1.w);
    *(ushort8*)(xh + (size_t)i * 8) = o;
}

// ---------------------------------------------------------------------------
// Pack weights into MFMA B-fragment order.
// B_h[k][c] (K=256: rows 0-127 = w_l_h^T, 128-255 = w_r_h^T), fragment
// layout for mfma_f32_16x16x32_bf16: lane l holds B[k=32*kk+8*(l>>4)+j][c=16*nr+(l&15)].
// Bfrag index = ((h*64 + kk*8 + nr)*64 + l)*8 + j.
// ---------------------------------------------------------------------------
__global__ __launch_bounds__(256) void bfrag_kernel(
    const float* __restrict__ wpl, const float* __restrict__ wpr,
    const float* __restrict__ wnl, const float* __restrict__ wnr,
    unsigned short* __restrict__ Bfrag) {
    int tid = blockIdx.x * 256 + threadIdx.x;   // 0..8191
    int l  = tid & 63;
    int nr = (tid >> 6) & 7;
    int kk = (tid >> 9) & 7;
    int h  = tid >> 12;
    const float* wl = h ? wnl : wpl;
    const float* wr = h ? wnr : wpr;
    int c  = nr * 16 + (l & 15);
    int k0 = kk * 32 + (l >> 4) * 8;
    ushort8 o;
#pragma unroll
    for (int j = 0; j < 8; ++j) {
        int k = k0 + j;
        float v = (k < 128) ? wl[c * 128 + k] : wr[c * 128 + (k - 128)];
        o[j] = f2bf(v);
    }
    *(ushort8*)(Bfrag + (size_t)tid * 8) = o;
}

// ---------------------------------------------------------------------------
// CSR build pass 1: per-(sign,dst) edge counts.
// ---------------------------------------------------------------------------
__global__ __launch_bounds__(256) void count_kernel(
    const int* __restrict__ ei, const float* __restrict__ attr,
    int* __restrict__ counts, int E, int N) {
    int e = blockIdx.x * 256 + threadIdx.x;
    if (e >= E) return;
    float w = attr[e];
    if (w == 0.f) return;
    int h = (w > 0.f) ? 0 : 1;
    int dst = ei[E + e];
    atomicAdd(&counts[h * N + dst], 1);
}

// ---------------------------------------------------------------------------
// Exclusive scan over counts[0..n): chunked (1024/block).
// ---------------------------------------------------------------------------
__global__ __launch_bounds__(256) void scan_k1(
    const int* __restrict__ counts, int* __restrict__ partial, int n) {
    __shared__ int sd[256];
    int b = blockIdx.x, t = threadIdx.x;
    int idx = b * SCAN_CHUNK + t * 4;
    int s = 0;
#pragma unroll
    for (int j = 0; j < 4; ++j) { int i = idx + j; if (i < n) s += counts[i]; }
    sd[t] = s;
    __syncthreads();
    for (int off = 128; off > 0; off >>= 1) {
        if (t < off) sd[t] += sd[t + off];
        __syncthreads();
    }
    if (t == 0) partial[b] = sd[0];
}

__global__ __launch_bounds__(128) void scan_k2(
    const int* __restrict__ partial, int* __restrict__ base, int nb) {
    __shared__ int sd[128];
    int t = threadIdx.x;
    int own = (t < nb) ? partial[t] : 0;
    sd[t] = own;
    __syncthreads();
    for (int off = 1; off < 128; off <<= 1) {
        int v = (t >= off) ? sd[t - off] : 0;
        __syncthreads();
        sd[t] += v;
        __syncthreads();
    }
    if (t < nb) base[t] = sd[t] - own;   // exclusive
}

__global__ __launch_bounds__(256) void scan_k3(
    const int* __restrict__ counts, const int* __restrict__ base,
    int* __restrict__ offs, int* __restrict__ cursor, int n) {
    __shared__ int sd[256];
    int b = blockIdx.x, t = threadIdx.x;
    int idx = b * SCAN_CHUNK + t * 4;
    int c[4]; int s = 0;
#pragma unroll
    for (int j = 0; j < 4; ++j) { int i = idx + j; c[j] = (i < n) ? counts[i] : 0; s += c[j]; }
    sd[t] = s;
    __syncthreads();
    for (int off = 1; off < 256; off <<= 1) {   // inclusive Hillis-Steele
        int v = (t >= off) ? sd[t - off] : 0;
        __syncthreads();
        sd[t] += v;
        __syncthreads();
    }
    int run = base[b] + sd[t] - s;
#pragma unroll
    for (int j = 0; j < 4; ++j) {
        int i = idx + j;
        if (i < n) { offs[i] = run; cursor[i] = run; run += c[j]; }
    }
}

// ---------------------------------------------------------------------------
// CSR build pass 2: scatter packed (src, |w|) records into per-row segments.
// ---------------------------------------------------------------------------
__global__ __launch_bounds__(256) void scatter_kernel(
    const int* __restrict__ ei, const float* __restrict__ attr,
    int* __restrict__ cursor, int2* __restrict__ edata, int E, int N) {
    int e = blockIdx.x * 256 + threadIdx.x;
    if (e >= E) return;
    float w = attr[e];
    if (w == 0.f) return;
    int h = (w > 0.f) ? 0 : 1;
    int dst = ei[E + e];
    int slot = atomicAdd(&cursor[h * N + dst], 1);
    edata[slot] = make_int2(ei[e], __float_as_int(fabsf(w)));
}

// ---------------------------------------------------------------------------
// Aggregation: one wave per (sign,dst) row; lane holds features 2l, 2l+1.
// Edges processed in batches of 8: load 8 packed (src,w) records, issue 8
// independent 4B gathers (deep MLP), then 16 FMAs. Tail padded with w=0.
// Epilogue divides by count and stores the bf16 row (coalesced 4B/lane).
// ---------------------------------------------------------------------------
__global__ __launch_bounds__(256) void agg_kernel(
    const unsigned short* __restrict__ xh, const int2* __restrict__ edata,
    const int* __restrict__ counts, const int* __restrict__ offs,
    unsigned short* __restrict__ mh, int twoN) {
    const int r = blockIdx.x * 4 + (threadIdx.x >> 6);
    if (r >= twoN) return;
    const int lane = threadIdx.x & 63;
    const int cn  = counts[r];
    const int beg = offs[r];
    float a0 = 0.f, a1 = 0.f;
    for (int j0 = 0; j0 < cn; j0 += 8) {
        int2 ed[8];
#pragma unroll
        for (int i = 0; i < 8; ++i)
            ed[i] = (j0 + i < cn) ? edata[beg + j0 + i] : make_int2(0, 0);
        unsigned xv[8];
#pragma unroll
        for (int i = 0; i < 8; ++i)
            xv[i] = *(const unsigned*)(xh + (size_t)ed[i].x * 128 + 2 * lane);
#pragma unroll
        for (int i = 0; i < 8; ++i) {
            const float wc = __int_as_float(ed[i].y);
            a0 = fmaf(__uint_as_float(xv[i] << 16), wc, a0);
            a1 = fmaf(__uint_as_float(xv[i] & 0xffff0000u), wc, a1);
        }
    }
    const float inv = 1.f / fmaxf((float)cn, 1.f);
    unsigned p = ((unsigned)f2bf(a1 * inv) << 16) | (unsigned)f2bf(a0 * inv);
    *(unsigned*)(mh + (size_t)r * 128 + 2 * lane) = p;
}

// ---------------------------------------------------------------------------
// Output GEMM via MFMA. grid = (ceil(N/128), 2), block 256 (4 waves).
// Wave w computes rows m0 = bx*128 + w*32 (2 M-frags), all 128 cols of its
// half. K=256: kk 0..3 read mean_h, kk 4..7 read x. A-frags loaded straight
// from global (16B/lane, row-major bf16); B-frags from fragment-packed
// global (coalesced, L2-resident). No LDS, no barriers.
// ---------------------------------------------------------------------------
__global__ __launch_bounds__(256) void out_mfma(
    const unsigned short* __restrict__ mh, const unsigned short* __restrict__ xh,
    const unsigned short* __restrict__ Bfrag,
    const float* __restrict__ bpos, const float* __restrict__ bneg,
    float* __restrict__ out, int N) {
    const int h  = blockIdx.y;
    const int l  = threadIdx.x & 63;
    const int wv = threadIdx.x >> 6;
    const int m0 = blockIdx.x * 128 + wv * 32;
    const int lm = l & 15;
    const int lk = l >> 4;

    const unsigned short* Am = mh + (size_t)h * N * 128;
    const bf16x8* Bf = (const bf16x8*)Bfrag + (size_t)h * 4096;

    f32x4 acc[2][8];
#pragma unroll
    for (int mr = 0; mr < 2; ++mr)
#pragma unroll
        for (int nr = 0; nr < 8; ++nr)
            acc[mr][nr] = (f32x4){0.f, 0.f, 0.f, 0.f};

    int r0 = m0 + lm;       if (r0 > N - 1) r0 = N - 1;
    int r1 = m0 + 16 + lm;  if (r1 > N - 1) r1 = N - 1;

#pragma unroll
    for (int kk = 0; kk < 8; ++kk) {
        const unsigned short* Asrc = (kk < 4) ? Am : xh;
        const int kloc = (kk & 3) * 32 + lk * 8;
        bf16x8 a0 = *(const bf16x8*)(Asrc + (size_t)r0 * 128 + kloc);
        bf16x8 a1 = *(const bf16x8*)(Asrc + (size_t)r1 * 128 + kloc);
        const bf16x8* bk = Bf + kk * 8 * 64;
#pragma unroll
        for (int nr = 0; nr < 8; ++nr) {
            bf16x8 b = bk[nr * 64 + l];
            acc[0][nr] = __builtin_amdgcn_mfma_f32_16x16x32_bf16(a0, b, acc[0][nr], 0, 0, 0);
            acc[1][nr] = __builtin_amdgcn_mfma_f32_16x16x32_bf16(a1, b, acc[1][nr], 0, 0, 0);
        }
    }

    const float* bb = (h == 0) ? bpos : bneg;
#pragma unroll
    for (int nr = 0; nr < 8; ++nr) {
        const float bc = bb[nr * 16 + lm];
#pragma unroll
        for (int mr = 0; mr < 2; ++mr) {
#pragma unroll
            for (int rr = 0; rr < 4; ++rr) {
                const int row = m0 + mr * 16 + lk * 4 + rr;
                if (row < N)
                    out[(size_t)row * 256 + h * 128 + nr * 16 + lm] =
                        fmaxf(acc[mr][nr][rr] + bc, 0.f);
            }
        }
    }
}

// ---------------------------------------------------------------------------
extern "C" void kernel_launch(void* const* d_in, const int* in_sizes, int n_in,
                              void* d_out, int out_size, void* d_ws, size_t ws_size,
                              hipStream_t stream) {
    const float* x    = (const float*)d_in[0];
    const int*   ei   = (const int*)d_in[1];
    const float* attr = (const float*)d_in[2];
    const float* wpl  = (const float*)d_in[3];
    const float* wpr  = (const float*)d_in[4];
    const float* bpos = (const float*)d_in[5];
    const float* wnl  = (const float*)d_in[6];
    const float* wnr  = (const float*)d_in[7];
    const float* bneg = (const float*)d_in[8];
    float* out = (float*)d_out;

    const int N = in_sizes[0] / 128;   // 50000
    const int E = in_sizes[2];         // 800000
    const int twoN = 2 * N;

    // Workspace layout:
    //   mh     ushort [2N][128]    bf16 per-sign means (already divided)
    //   xh     ushort [N][128]     bf16 features
    //   Bfrag  ushort [2][4096][8] fragment-packed weights
    //   edata  int2   [E]          packed (src, |w|) CSR records
    //   counts,offs,cursor int [2N]
    //   partial,base int [128]
    unsigned short* mh    = (unsigned short*)d_ws;
    unsigned short* xh    = mh + (size_t)twoN * 128;
    unsigned short* Bfrag = xh + (size_t)N * 128;
    int2* edata  = (int2*)(Bfrag + 65536);
    int* counts  = (int*)(edata + E);
    int* offs    = counts + twoN;
    int* cursor  = offs + twoN;
    int* partial = cursor + twoN;
    int* sbase   = partial + 128;

    const int nchunk = (twoN + SCAN_CHUNK - 1) / SCAN_CHUNK;   // 98 (<=128)

    hipMemsetAsync(counts, 0, (size_t)twoN * sizeof(int), stream);

    xcvt_kernel<<<(N * 16 + 255) / 256, 256, 0, stream>>>(x, xh, N * 16);
    bfrag_kernel<<<32, 256, 0, stream>>>(wpl, wpr, wnl, wnr, Bfrag);
    count_kernel<<<(E + 255) / 256, 256, 0, stream>>>(ei, attr, counts, E, N);
    scan_k1<<<nchunk, 256, 0, stream>>>(counts, partial, twoN);
    scan_k2<<<1, 128, 0, stream>>>(partial, sbase, nchunk);
    scan_k3<<<nchunk, 256, 0, stream>>>(counts, sbase, offs, cursor, twoN);
    scatter_kernel<<<(E + 255) / 256, 256, 0, stream>>>(ei, attr, cursor, edata, E, N);
    agg_kernel<<<(twoN + 3) / 4, 256, 0, stream>>>(xh, edata, counts, offs, mh, twoN);
    out_mfma<<<dim3((N + 127) / 128, 2), 256, 0, stream>>>(mh, xh, Bfrag, bpos, bneg, out, N);
}